// Round 1
// baseline (493.730 us; speedup 1.0000x reference)
//
#include <hip/hip_runtime.h>
#include <hip/hip_bf16.h>

#define TOKENS 8192
#define DM 1024
#define DFF 4096
#define NE 8
#define CAP 1280
#define ECAP (NE*CAP)                     // 10240
#define OUT_ELEMS ((size_t)NE*CAP*DFF)    // 41,943,040
#define CMB_ELEMS ((size_t)TOKENS*NE*CAP) // 83,886,080

typedef __attribute__((ext_vector_type(8))) short short8;
typedef __attribute__((ext_vector_type(4))) float f32x4;

__device__ inline ushort f2bf(float f) {
    __hip_bfloat16 h = __float2bfloat16(f);
    return *reinterpret_cast<ushort*>(&h);
}

union U8 { short8 s; ushort4 u[2]; };
__device__ inline short8 pack8(ushort4 lo, ushort4 hi) {
    U8 t; t.u[0] = lo; t.u[1] = hi; return t.s;
}

// ---------------- gate: logits, softmax, top1 ----------------
__global__ __launch_bounds__(256) void gate_kernel(const float* __restrict__ x,
        const float* __restrict__ gw, float* __restrict__ probs8, int* __restrict__ top1) {
    int wave = threadIdx.x >> 6;
    int lane = threadIdx.x & 63;
    int t = blockIdx.x * 4 + wave;
    const float* xrow = x + (size_t)t * DM;
    float xr[16];
    #pragma unroll
    for (int j = 0; j < 16; ++j) xr[j] = xrow[j * 64 + lane];
    float logit[8];
    #pragma unroll
    for (int e = 0; e < 8; ++e) {
        const float* g = gw + e * DM;
        float s = 0.f;
        #pragma unroll
        for (int j = 0; j < 16; ++j) s += xr[j] * g[j * 64 + lane];
        #pragma unroll
        for (int off = 32; off >= 1; off >>= 1) s += __shfl_xor(s, off);
        logit[e] = s;
    }
    if (lane == 0) {
        int bi = 0; float bv = logit[0];
        #pragma unroll
        for (int e = 1; e < 8; ++e) if (logit[e] > bv) { bv = logit[e]; bi = e; }
        float se = 0.f, p[8];
        #pragma unroll
        for (int e = 0; e < 8; ++e) { p[e] = expf(logit[e] - bv); se += p[e]; }
        float inv = 1.f / se;
        #pragma unroll
        for (int e = 0; e < 8; ++e) probs8[t * 8 + e] = p[e] * inv;
        top1[t] = bi;
    }
}

// ---------------- rank: per-expert cumsum scan, counts, me, l_aux ----------------
__global__ __launch_bounds__(512) void rank_kernel(const int* __restrict__ top1,
        const float* __restrict__ probs8, int* __restrict__ slot_token,
        float* __restrict__ laux) {
    int w = threadIdx.x >> 6;      // wave = expert
    int lane = threadIdx.x & 63;
    __shared__ float me_sh[8];
    __shared__ int cnt_sh[8];
    for (int i = threadIdx.x; i < ECAP; i += 512) slot_token[i] = -1;
    __syncthreads();

    int base = 0;
    for (int t0 = 0; t0 < TOKENS; t0 += 256) {
        int idx[4];
        #pragma unroll
        for (int q = 0; q < 4; ++q) idx[q] = top1[t0 + q * 64 + lane];
        #pragma unroll
        for (int q = 0; q < 4; ++q) {
            bool mine = (idx[q] == w);
            unsigned long long m = __ballot(mine);
            if (mine) {
                int r = base + __popcll(m & ((1ull << lane) - 1ull));
                if (r < CAP) slot_token[w * CAP + r] = t0 + q * 64 + lane;
            }
            base += __popcll(m);
        }
    }
    if (lane == 0) cnt_sh[w] = base;

    float s = 0.f;
    for (int t = lane; t < TOKENS; t += 64) s += probs8[t * 8 + w];
    #pragma unroll
    for (int off = 32; off >= 1; off >>= 1) s += __shfl_xor(s, off);
    if (lane == 0) me_sh[w] = s;
    __syncthreads();
    if (threadIdx.x == 0) {
        float la = 0.f;
        #pragma unroll
        for (int e = 0; e < 8; ++e)
            la += (me_sh[e] / (float)TOKENS) * ((float)cnt_sh[e] / (float)TOKENS);
        laux[0] = la * (float)NE;
    }
}

// ---------------- convert x -> bf16 ----------------
__global__ __launch_bounds__(256) void cvt_x(const float* __restrict__ x, ushort* __restrict__ xbf) {
    size_t i = ((size_t)blockIdx.x * 256 + threadIdx.x) * 4;
    float4 v = *(const float4*)(x + i);
    ushort4 o;
    o.x = f2bf(v.x); o.y = f2bf(v.y); o.z = f2bf(v.z); o.w = f2bf(v.w);
    *(ushort4*)(xbf + i) = o;
}

// ---------------- convert+transpose W: [8][1024][4096] f32 -> [8][4096][1024] bf16 ----------------
__global__ __launch_bounds__(256) void cvt_w(const float* __restrict__ w, ushort* __restrict__ wt) {
    int e = blockIdx.z;
    int n0 = blockIdx.x * 32;
    int k0 = blockIdx.y * 32;
    __shared__ float tile[32][33];
    const float* we = w + (size_t)e * DM * DFF;
    int c = threadIdx.x & 31, r0 = threadIdx.x >> 5;
    #pragma unroll
    for (int i = 0; i < 4; ++i) {
        int r = r0 + i * 8;
        tile[r][c] = we[(size_t)(k0 + r) * DFF + n0 + c];
    }
    __syncthreads();
    ushort* wte = wt + (size_t)e * DFF * DM;
    #pragma unroll
    for (int i = 0; i < 4; ++i) {
        int r = r0 + i * 8;  // n offset within tile
        wte[(size_t)(n0 + r) * DM + k0 + c] = f2bf(tile[c][r]);
    }
}

// ---------------- gathered GEMM: out[e][c][f] = xbf[tok(e,c)] @ Wt[e] + bias ----------------
__global__ __launch_bounds__(256) void gemm_kernel(
    const ushort* __restrict__ xbf,      // [8192][1024] bf16
    const ushort* __restrict__ wt,       // [8][4096][1024] bf16 (n-major)
    const float*  __restrict__ bias,     // [8][4096]
    const int*    __restrict__ slot_token, // [8][1280]
    float* __restrict__ out)             // [8][1280][4096]
{
    const int e = blockIdx.z;
    const int mt = blockIdx.y;   // 0..9
    const int nt = blockIdx.x;   // 0..31
    __shared__ __align__(16) short As[128 * 32]; // [m][kg(4)][8 bf16]   64B/row
    __shared__ __align__(16) short Bs[128 * 32]; // [n][kg(4)][8 bf16]
    const int tid  = threadIdx.x;
    const int lane = tid & 63;
    const int wave = tid >> 6;
    const int wr = wave >> 1, wc = wave & 1;

    // staging: thread owns groups tid and tid+256; group g -> row g>>2, kg g&3
    const int arow0 = tid >> 2, kg = tid & 3;
    const int tokA0 = slot_token[e * CAP + mt * 128 + arow0];
    const int tokA1 = slot_token[e * CAP + mt * 128 + arow0 + 64];
    const ushort* wrow0 = wt + ((size_t)e * DFF + (size_t)nt * 128 + arow0) * DM;
    const ushort* wrow1 = wrow0 + (size_t)64 * DM;
    const ushort* xr0 = (tokA0 >= 0) ? (xbf + (size_t)tokA0 * DM) : nullptr;
    const ushort* xr1 = (tokA1 >= 0) ? (xbf + (size_t)tokA1 * DM) : nullptr;

    ushort4 zero4; zero4.x = zero4.y = zero4.z = zero4.w = 0;
    ushort4 a0lo, a0hi, a1lo, a1hi, b0lo, b0hi, b1lo, b1hi;

    #define LOADTILE(K0) do { \
        a0lo = xr0 ? *(const ushort4*)(xr0 + (K0) + kg * 4)      : zero4; \
        a0hi = xr0 ? *(const ushort4*)(xr0 + (K0) + 16 + kg * 4) : zero4; \
        a1lo = xr1 ? *(const ushort4*)(xr1 + (K0) + kg * 4)      : zero4; \
        a1hi = xr1 ? *(const ushort4*)(xr1 + (K0) + 16 + kg * 4) : zero4; \
        b0lo = *(const ushort4*)(wrow0 + (K0) + kg * 4); \
        b0hi = *(const ushort4*)(wrow0 + (K0) + 16 + kg * 4); \
        b1lo = *(const ushort4*)(wrow1 + (K0) + kg * 4); \
        b1hi = *(const ushort4*)(wrow1 + (K0) + 16 + kg * 4); \
    } while (0)

    f32x4 acc[4][4];
    #pragma unroll
    for (int mi = 0; mi < 4; ++mi)
        #pragma unroll
        for (int ni = 0; ni < 4; ++ni)
            acc[mi][ni] = (f32x4){0.f, 0.f, 0.f, 0.f};

    LOADTILE(0);
    for (int ks = 0; ks < 32; ++ks) {
        __syncthreads();
        *(short8*)(&As[(size_t)tid * 8])         = pack8(a0lo, a0hi);
        *(short8*)(&As[((size_t)tid + 256) * 8]) = pack8(a1lo, a1hi);
        *(short8*)(&Bs[(size_t)tid * 8])         = pack8(b0lo, b0hi);
        *(short8*)(&Bs[((size_t)tid + 256) * 8]) = pack8(b1lo, b1hi);
        if (ks < 31) LOADTILE((ks + 1) * 32);
        __syncthreads();

        short8 af[4], bfr[4];
        #pragma unroll
        for (int mi = 0; mi < 4; ++mi)
            af[mi] = *(const short8*)(&As[(wr * 64 + mi * 16 + (lane & 15)) * 32 + (lane >> 4) * 8]);
        #pragma unroll
        for (int ni = 0; ni < 4; ++ni)
            bfr[ni] = *(const short8*)(&Bs[(wc * 64 + ni * 16 + (lane & 15)) * 32 + (lane >> 4) * 8]);
        #pragma unroll
        for (int mi = 0; mi < 4; ++mi)
            #pragma unroll
            for (int ni = 0; ni < 4; ++ni)
                acc[mi][ni] = __builtin_amdgcn_mfma_f32_16x16x32_bf16(af[mi], bfr[ni], acc[mi][ni], 0, 0, 0);
    }
    #undef LOADTILE

    float* orow = out + ((size_t)e * CAP + (size_t)mt * 128) * DFF + (size_t)nt * 128;
    #pragma unroll
    for (int ni = 0; ni < 4; ++ni) {
        int c = wc * 64 + ni * 16 + (lane & 15);
        float bv = bias[e * DFF + nt * 128 + c];
        #pragma unroll
        for (int mi = 0; mi < 4; ++mi) {
            #pragma unroll
            for (int j = 0; j < 4; ++j) {
                int r = wr * 64 + mi * 16 + (lane >> 4) * 4 + j;
                orow[(size_t)r * DFF + c] = acc[mi][ni][j] + bv;
            }
        }
    }
}

// ---------------- scatter combine_weights + l_aux ----------------
__global__ __launch_bounds__(256) void scatter_kernel(const int* __restrict__ slot_token,
        const float* __restrict__ probs8, const float* __restrict__ laux,
        float* __restrict__ cmb, float* __restrict__ laux_out) {
    int s = blockIdx.x * 256 + threadIdx.x;   // 0..10239
    if (s < ECAP) {
        int tok = slot_token[s];
        if (tok >= 0) {
            int e = s / CAP;
            cmb[(size_t)tok * ECAP + s] = probs8[tok * 8 + e];
        }
    }
    if (blockIdx.x == 0 && threadIdx.x == 0) laux_out[0] = laux[0];
}

extern "C" void kernel_launch(void* const* d_in, const int* in_sizes, int n_in,
                              void* d_out, int out_size, void* d_ws, size_t ws_size,
                              hipStream_t stream) {
    const float* x  = (const float*)d_in[0];
    const float* gw = (const float*)d_in[1];
    const float* ew = (const float*)d_in[2];
    const float* eb = (const float*)d_in[3];

    float* out = (float*)d_out;                 // [8][1280][4096]
    float* cmb = out + OUT_ELEMS;               // [8192][8][1280]
    float* laux_out = cmb + CMB_ELEMS;          // scalar

    // small scratch in d_ws
    float* probs8 = (float*)d_ws;               // 8192*8
    int* top1 = (int*)(probs8 + TOKENS * 8);    // 8192
    int* slot_token = top1 + TOKENS;            // 10240
    float* laux_ws = (float*)(slot_token + ECAP);

    // big bf16 scratch inside the combine region (zeroed afterwards)
    ushort* wtbf = (ushort*)cmb;                       // 8*4096*1024 bf16 = 64 MB
    ushort* xbf  = wtbf + (size_t)NE * DFF * DM;       // 8192*1024 bf16 = 16 MB

    gate_kernel<<<TOKENS / 4, 256, 0, stream>>>(x, gw, probs8, top1);
    rank_kernel<<<1, 512, 0, stream>>>(top1, probs8, slot_token, laux_ws);
    cvt_x<<<(TOKENS * DM) / (256 * 4), 256, 0, stream>>>(x, xbf);
    cvt_w<<<dim3(DFF / 32, DM / 32, NE), 256, 0, stream>>>(ew, wtbf);
    gemm_kernel<<<dim3(DFF / 128, CAP / 128, NE), 256, 0, stream>>>(xbf, wtbf, eb, slot_token, out);
    hipMemsetAsync(cmb, 0, CMB_ELEMS * sizeof(float), stream);
    scatter_kernel<<<(ECAP + 255) / 256, 256, 0, stream>>>(slot_token, probs8, laux_ws, cmb, laux_out);
}

// Round 2
// 315.937 us; speedup vs baseline: 1.5627x; 1.5627x over previous
//
#include <hip/hip_runtime.h>
#include <hip/hip_bf16.h>

#define TOKENS 8192
#define DM 1024
#define DFF 4096
#define NE 8
#define CAP 1280
#define ECAP (NE*CAP)                     // 10240
#define OUT_ELEMS ((size_t)NE*CAP*DFF)    // 41,943,040
#define CMB_ELEMS ((size_t)TOKENS*NE*CAP) // 83,886,080
#define ZROW TOKENS                       // index of appended zero row in xbf

typedef __attribute__((ext_vector_type(8))) short short8;
typedef __attribute__((ext_vector_type(4))) float f32x4;

__device__ inline ushort f2bf(float f) {
    __hip_bfloat16 h = __float2bfloat16(f);
    return *reinterpret_cast<ushort*>(&h);
}

__device__ __forceinline__ void gload16(const ushort* g, short* l) {
    __builtin_amdgcn_global_load_lds(
        (const __attribute__((address_space(1))) void*)g,
        (__attribute__((address_space(3))) void*)l, 16, 0, 0);
}

// ---------------- gate: logits, softmax, top1 ----------------
__global__ __launch_bounds__(256) void gate_kernel(const float* __restrict__ x,
        const float* __restrict__ gw, float* __restrict__ probs8, int* __restrict__ top1) {
    int wave = threadIdx.x >> 6;
    int lane = threadIdx.x & 63;
    int t = blockIdx.x * 4 + wave;
    const float* xrow = x + (size_t)t * DM;
    float xr[16];
    #pragma unroll
    for (int j = 0; j < 16; ++j) xr[j] = xrow[j * 64 + lane];
    float logit[8];
    #pragma unroll
    for (int e = 0; e < 8; ++e) {
        const float* g = gw + e * DM;
        float s = 0.f;
        #pragma unroll
        for (int j = 0; j < 16; ++j) s += xr[j] * g[j * 64 + lane];
        #pragma unroll
        for (int off = 32; off >= 1; off >>= 1) s += __shfl_xor(s, off);
        logit[e] = s;
    }
    if (lane == 0) {
        int bi = 0; float bv = logit[0];
        #pragma unroll
        for (int e = 1; e < 8; ++e) if (logit[e] > bv) { bv = logit[e]; bi = e; }
        float se = 0.f, p[8];
        #pragma unroll
        for (int e = 0; e < 8; ++e) { p[e] = expf(logit[e] - bv); se += p[e]; }
        float inv = 1.f / se;
        #pragma unroll
        for (int e = 0; e < 8; ++e) probs8[t * 8 + e] = p[e] * inv;
        top1[t] = bi;
    }
}

// ---------------- rank: per-expert cumsum scan, counts, me, l_aux ----------------
__global__ __launch_bounds__(512) void rank_kernel(const int* __restrict__ top1,
        const float* __restrict__ probs8, int* __restrict__ slot_token,
        float* __restrict__ laux) {
    int w = threadIdx.x >> 6;      // wave = expert
    int lane = threadIdx.x & 63;
    __shared__ float me_sh[8];
    __shared__ int cnt_sh[8];
    for (int i = threadIdx.x; i < ECAP; i += 512) slot_token[i] = ZROW;
    __syncthreads();

    int base = 0;
    for (int t0 = 0; t0 < TOKENS; t0 += 256) {
        int idx[4];
        #pragma unroll
        for (int q = 0; q < 4; ++q) idx[q] = top1[t0 + q * 64 + lane];
        #pragma unroll
        for (int q = 0; q < 4; ++q) {
            bool mine = (idx[q] == w);
            unsigned long long m = __ballot(mine);
            if (mine) {
                int r = base + __popcll(m & ((1ull << lane) - 1ull));
                if (r < CAP) slot_token[w * CAP + r] = t0 + q * 64 + lane;
            }
            base += __popcll(m);
        }
    }
    if (lane == 0) cnt_sh[w] = base;

    float s = 0.f;
    for (int t = lane; t < TOKENS; t += 64) s += probs8[t * 8 + w];
    #pragma unroll
    for (int off = 32; off >= 1; off >>= 1) s += __shfl_xor(s, off);
    if (lane == 0) me_sh[w] = s;
    __syncthreads();
    if (threadIdx.x == 0) {
        float la = 0.f;
        #pragma unroll
        for (int e = 0; e < 8; ++e)
            la += (me_sh[e] / (float)TOKENS) * ((float)cnt_sh[e] / (float)TOKENS);
        laux[0] = la * (float)NE;
    }
}

// ---------------- convert x -> bf16 (+ zero row at index TOKENS) ----------------
__global__ __launch_bounds__(256) void cvt_x(const float* __restrict__ x, ushort* __restrict__ xbf) {
    size_t i = ((size_t)blockIdx.x * 256 + threadIdx.x) * 4;
    ushort4 o;
    if (i < (size_t)TOKENS * DM) {
        float4 v = *(const float4*)(x + i);
        o.x = f2bf(v.x); o.y = f2bf(v.y); o.z = f2bf(v.z); o.w = f2bf(v.w);
    } else {
        o.x = o.y = o.z = o.w = 0;
    }
    *(ushort4*)(xbf + i) = o;
}

// ---------------- convert+transpose W: [8][1024][4096] f32 -> [8][4096][1024] bf16 ----------------
__global__ __launch_bounds__(256) void cvt_w(const float* __restrict__ w, ushort* __restrict__ wt) {
    int e = blockIdx.z;
    int n0 = blockIdx.x * 32;
    int k0 = blockIdx.y * 32;
    __shared__ float tile[32][33];
    const float* we = w + (size_t)e * DM * DFF;
    int c = threadIdx.x & 31, r0 = threadIdx.x >> 5;
    #pragma unroll
    for (int i = 0; i < 4; ++i) {
        int r = r0 + i * 8;
        tile[r][c] = we[(size_t)(k0 + r) * DFF + n0 + c];
    }
    __syncthreads();
    ushort* wte = wt + (size_t)e * DFF * DM;
    #pragma unroll
    for (int i = 0; i < 4; ++i) {
        int r = r0 + i * 8;  // n offset within tile
        wte[(size_t)(n0 + r) * DM + k0 + c] = f2bf(tile[c][r]);
    }
}

// ---------------- gathered GEMM: out[e][c][f] = xbf[tok(e,c)] @ Wt[e] + bias ----------------
// LDS layout per buffer: A then B, each 512 16B-slots. Slot g (written linearly by
// global_load_lds, lane l of wave w -> slot w*64+l within issue segment) holds
// (row = g>>2, kg = (g&3) ^ ((g>>3)&3)); i.e. fragment read addr
// slot(r,c) = r*4 + (c ^ ((r>>1)&3)) -> each quarter-wave covers all 8 bank-slots 2x.
__global__ __launch_bounds__(256) void gemm_kernel(
    const ushort* __restrict__ xbf,      // [8193][1024] bf16 (row 8192 = zeros)
    const ushort* __restrict__ wt,       // [8][4096][1024] bf16 (n-major)
    const float*  __restrict__ bias,     // [8][4096]
    const int*    __restrict__ slot_token, // [8][1280], empty -> ZROW
    float* __restrict__ out)             // [8][1280][4096]
{
    const int e = blockIdx.z;
    const int mt = blockIdx.y;   // 0..9
    const int nt = blockIdx.x;   // 0..31
    __shared__ __align__(16) short lds[2][8192]; // [buf][A 4096 | B 4096] shorts
    const int tid  = threadIdx.x;
    const int lane = tid & 63;
    const int wave = tid >> 6;
    const int wr = wave >> 1, wc = wave & 1;

    // staging: thread tid owns slots tid and tid+256 of both A and B
    const int row = tid >> 2;                       // 0..63
    const int kg  = (tid & 3) ^ ((tid >> 3) & 3);   // inverse swizzle
    const int tokA0 = slot_token[e * CAP + mt * 128 + row];
    const int tokA1 = slot_token[e * CAP + mt * 128 + row + 64];
    const ushort* aptr0 = xbf + (size_t)tokA0 * DM + kg * 8;
    const ushort* aptr1 = xbf + (size_t)tokA1 * DM + kg * 8;
    const ushort* bptr0 = wt + ((size_t)e * DFF + (size_t)nt * 128 + row) * DM + kg * 8;
    const ushort* bptr1 = bptr0 + (size_t)64 * DM;
    short* const ldsA0 = &lds[0][0] + (size_t)wave * 64 * 8;
    short* const ldsB0 = &lds[0][4096] + (size_t)wave * 64 * 8;

    #define STAGE(K, B) do { \
        size_t ko = (size_t)(K) * 32; \
        short* la = ldsA0 + (size_t)(B) * 8192; \
        short* lb = ldsB0 + (size_t)(B) * 8192; \
        gload16(aptr0 + ko, la); \
        gload16(aptr1 + ko, la + 256 * 8); \
        gload16(bptr0 + ko, lb); \
        gload16(bptr1 + ko, lb + 256 * 8); \
    } while (0)

    f32x4 acc[4][4];
    #pragma unroll
    for (int mi = 0; mi < 4; ++mi)
        #pragma unroll
        for (int ni = 0; ni < 4; ++ni)
            acc[mi][ni] = (f32x4){0.f, 0.f, 0.f, 0.f};

    // precompute fragment slot offsets (short index)
    int aslot[4], bslot[4];
    #pragma unroll
    for (int mi = 0; mi < 4; ++mi) {
        int r = wr * 64 + mi * 16 + (lane & 15);
        int c = lane >> 4;
        aslot[mi] = (r * 4 + (c ^ ((r >> 1) & 3))) * 8;
    }
    #pragma unroll
    for (int ni = 0; ni < 4; ++ni) {
        int r = wc * 64 + ni * 16 + (lane & 15);
        int c = lane >> 4;
        bslot[ni] = 4096 + (r * 4 + (c ^ ((r >> 1) & 3))) * 8;
    }

    STAGE(0, 0);
    int cur = 0;
    for (int ks = 0; ks < 32; ++ks) {
        __syncthreads();                 // staged tile ks visible (compiler drains vmcnt)
        if (ks < 31) STAGE(ks + 1, cur ^ 1);
        const short* L = &lds[cur][0];
        short8 af[4], bfr[4];
        #pragma unroll
        for (int mi = 0; mi < 4; ++mi)
            af[mi] = *(const short8*)(L + aslot[mi]);
        #pragma unroll
        for (int ni = 0; ni < 4; ++ni)
            bfr[ni] = *(const short8*)(L + bslot[ni]);
        #pragma unroll
        for (int mi = 0; mi < 4; ++mi)
            #pragma unroll
            for (int ni = 0; ni < 4; ++ni)
                acc[mi][ni] = __builtin_amdgcn_mfma_f32_16x16x32_bf16(af[mi], bfr[ni], acc[mi][ni], 0, 0, 0);
        cur ^= 1;
    }
    #undef STAGE

    float* orow = out + ((size_t)e * CAP + (size_t)mt * 128) * DFF + (size_t)nt * 128;
    #pragma unroll
    for (int ni = 0; ni < 4; ++ni) {
        int c = wc * 64 + ni * 16 + (lane & 15);
        float bv = bias[e * DFF + nt * 128 + c];
        #pragma unroll
        for (int mi = 0; mi < 4; ++mi) {
            #pragma unroll
            for (int j = 0; j < 4; ++j) {
                int r = wr * 64 + mi * 16 + (lane >> 4) * 4 + j;
                orow[(size_t)r * DFF + c] = acc[mi][ni][j] + bv;
            }
        }
    }
}

// ---------------- scatter combine_weights + l_aux ----------------
__global__ __launch_bounds__(256) void scatter_kernel(const int* __restrict__ slot_token,
        const float* __restrict__ probs8, const float* __restrict__ laux,
        float* __restrict__ cmb, float* __restrict__ laux_out) {
    int s = blockIdx.x * 256 + threadIdx.x;   // 0..10239
    if (s < ECAP) {
        int tok = slot_token[s];
        if (tok < TOKENS) {
            int e = s / CAP;
            cmb[(size_t)tok * ECAP + s] = probs8[tok * 8 + e];
        }
    }
    if (blockIdx.x == 0 && threadIdx.x == 0) laux_out[0] = laux[0];
}

extern "C" void kernel_launch(void* const* d_in, const int* in_sizes, int n_in,
                              void* d_out, int out_size, void* d_ws, size_t ws_size,
                              hipStream_t stream) {
    const float* x  = (const float*)d_in[0];
    const float* gw = (const float*)d_in[1];
    const float* ew = (const float*)d_in[2];
    const float* eb = (const float*)d_in[3];

    float* out = (float*)d_out;                 // [8][1280][4096]
    float* cmb = out + OUT_ELEMS;               // [8192][8][1280]
    float* laux_out = cmb + CMB_ELEMS;          // scalar

    // small scratch in d_ws
    float* probs8 = (float*)d_ws;               // 8192*8
    int* top1 = (int*)(probs8 + TOKENS * 8);    // 8192
    int* slot_token = top1 + TOKENS;            // 10240
    float* laux_ws = (float*)(slot_token + ECAP);

    // big bf16 scratch inside the combine region (zeroed afterwards)
    ushort* wtbf = (ushort*)cmb;                       // 8*4096*1024 bf16 = 64 MB
    ushort* xbf  = wtbf + (size_t)NE * DFF * DM;       // 8193*1024 bf16 ≈ 16.8 MB

    gate_kernel<<<TOKENS / 4, 256, 0, stream>>>(x, gw, probs8, top1);
    rank_kernel<<<1, 512, 0, stream>>>(top1, probs8, slot_token, laux_ws);
    cvt_x<<<(TOKENS + 1) * DM / (256 * 4), 256, 0, stream>>>(x, xbf);
    cvt_w<<<dim3(DFF / 32, DM / 32, NE), 256, 0, stream>>>(ew, wtbf);
    gemm_kernel<<<dim3(DFF / 128, CAP / 128, NE), 256, 0, stream>>>(xbf, wtbf, eb, slot_token, out);
    hipMemsetAsync(cmb, 0, CMB_ELEMS * sizeof(float), stream);
    scatter_kernel<<<(ECAP + 255) / 256, 256, 0, stream>>>(slot_token, probs8, laux_ws, cmb, laux_out);
}

// Round 3
// 304.319 us; speedup vs baseline: 1.6224x; 1.0382x over previous
//
#include <hip/hip_runtime.h>
#include <hip/hip_bf16.h>

#define TOKENS 8192
#define DM 1024
#define DFF 4096
#define NE 8
#define CAP 1280
#define ECAP (NE*CAP)                     // 10240
#define OUT_ELEMS ((size_t)NE*CAP*DFF)    // 41,943,040
#define CMB_ELEMS ((size_t)TOKENS*NE*CAP) // 83,886,080
#define ZROW TOKENS                       // index of appended zero row in xbf
#define GBK 32                            // GEMM K-tile

typedef __attribute__((ext_vector_type(8))) short short8;
typedef __attribute__((ext_vector_type(4))) float f32x4;

__device__ inline ushort f2bf(float f) {
    __hip_bfloat16 h = __float2bfloat16(f);
    return *reinterpret_cast<ushort*>(&h);
}

__device__ __forceinline__ void gload16(const ushort* g, short* l) {
    __builtin_amdgcn_global_load_lds(
        (const __attribute__((address_space(1))) void*)g,
        (__attribute__((address_space(3))) void*)l, 16, 0, 0);
}

// ---------------- gate: logits, softmax, top1, x->bf16 fused ----------------
__global__ __launch_bounds__(256) void gate_kernel(const float* __restrict__ x,
        const float* __restrict__ gw, float* __restrict__ probs8, int* __restrict__ top1,
        ushort* __restrict__ xbf) {
    int wave = threadIdx.x >> 6;
    int lane = threadIdx.x & 63;
    int t = blockIdx.x * 4 + wave;
    const float* xrow = x + (size_t)t * DM;
    // lane holds elements lane*4 + j*256 .. +3  (perfectly coalesced float4)
    float4 xv[4];
    #pragma unroll
    for (int j = 0; j < 4; ++j) xv[j] = *(const float4*)(xrow + lane * 4 + j * 256);
    // emit bf16 row
    ushort* xbrow = xbf + (size_t)t * DM;
    #pragma unroll
    for (int j = 0; j < 4; ++j) {
        ushort4 o;
        o.x = f2bf(xv[j].x); o.y = f2bf(xv[j].y); o.z = f2bf(xv[j].z); o.w = f2bf(xv[j].w);
        *(ushort4*)(xbrow + lane * 4 + j * 256) = o;
    }
    float logit[8];
    #pragma unroll
    for (int e = 0; e < 8; ++e) {
        const float* g = gw + e * DM;
        float s = 0.f;
        #pragma unroll
        for (int j = 0; j < 4; ++j) {
            float4 gv = *(const float4*)(g + lane * 4 + j * 256);
            s += xv[j].x * gv.x + xv[j].y * gv.y + xv[j].z * gv.z + xv[j].w * gv.w;
        }
        #pragma unroll
        for (int off = 32; off >= 1; off >>= 1) s += __shfl_xor(s, off);
        logit[e] = s;
    }
    if (lane == 0) {
        int bi = 0; float bv = logit[0];
        #pragma unroll
        for (int e = 1; e < 8; ++e) if (logit[e] > bv) { bv = logit[e]; bi = e; }
        float se = 0.f, p[8];
        #pragma unroll
        for (int e = 0; e < 8; ++e) { p[e] = expf(logit[e] - bv); se += p[e]; }
        float inv = 1.f / se;
        #pragma unroll
        for (int e = 0; e < 8; ++e) probs8[t * 8 + e] = p[e] * inv;
        top1[t] = bi;
    }
    if (blockIdx.x == 0) {   // zero row for empty capacity slots
        ushort4 z; z.x = z.y = z.z = z.w = 0;
        *(ushort4*)(xbf + (size_t)ZROW * DM + threadIdx.x * 4) = z;
    }
}

// ---------------- rank: per-expert cumsum scan (top1 staged in LDS) ----------------
__global__ __launch_bounds__(512) void rank_kernel(const int* __restrict__ top1,
        const float* __restrict__ probs8, int* __restrict__ slot_token,
        float* __restrict__ laux) {
    int w = threadIdx.x >> 6;      // wave = expert
    int lane = threadIdx.x & 63;
    __shared__ int t1s[TOKENS];    // 32 KB
    __shared__ float me_sh[8];
    __shared__ int cnt_sh[8];
    for (int i = threadIdx.x; i < TOKENS; i += 512) t1s[i] = top1[i];
    for (int i = threadIdx.x; i < ECAP; i += 512) slot_token[i] = ZROW;
    __syncthreads();

    int base = 0;
    for (int t0 = 0; t0 < TOKENS; t0 += 256) {
        #pragma unroll
        for (int q = 0; q < 4; ++q) {
            bool mine = (t1s[t0 + q * 64 + lane] == w);
            unsigned long long m = __ballot(mine);
            if (mine) {
                int r = base + __popcll(m & ((1ull << lane) - 1ull));
                if (r < CAP) slot_token[w * CAP + r] = t0 + q * 64 + lane;
            }
            base += __popcll(m);
        }
    }
    if (lane == 0) cnt_sh[w] = base;

    float s = 0.f;
    for (int t = lane; t < TOKENS; t += 64) s += probs8[t * 8 + w];
    #pragma unroll
    for (int off = 32; off >= 1; off >>= 1) s += __shfl_xor(s, off);
    if (lane == 0) me_sh[w] = s;
    __syncthreads();
    if (threadIdx.x == 0) {
        float la = 0.f;
        #pragma unroll
        for (int e = 0; e < 8; ++e)
            la += (me_sh[e] / (float)TOKENS) * ((float)cnt_sh[e] / (float)TOKENS);
        laux[0] = la * (float)NE;
    }
}

// ---------------- convert+transpose W: [8][1024][4096] f32 -> [8][4096][1024] bf16 ----------------
__global__ __launch_bounds__(256) void cvt_w(const float* __restrict__ w, ushort* __restrict__ wt) {
    int e = blockIdx.z;
    int n0 = blockIdx.x * 32;
    int k0 = blockIdx.y * 32;
    __shared__ float tile[32][33];
    const float* we = w + (size_t)e * DM * DFF;
    int c = threadIdx.x & 31, r0 = threadIdx.x >> 5;
    #pragma unroll
    for (int i = 0; i < 4; ++i) {
        int r = r0 + i * 8;
        tile[r][c] = we[(size_t)(k0 + r) * DFF + n0 + c];
    }
    __syncthreads();
    ushort* wte = wt + (size_t)e * DFF * DM;
    #pragma unroll
    for (int i = 0; i < 4; ++i) {
        int r = r0 + i * 8;  // n offset within tile
        wte[(size_t)(n0 + r) * DM + k0 + c] = f2bf(tile[c][r]);
    }
}

// ---------------- gathered GEMM, 256x256 tile, BK=32, 4-buf deep pipeline ----------------
// LDS buffer (32KB): A 256rows x 32k (slots 0..1023) | B 256rows x 32k (slots 1024..2047).
// 16B slot s holds (row = s>>2, chunk = (s&3) ^ ((s>>3)&3)); fragment read addr
// slot(r,c) = r*4 + (c ^ ((r>>1)&3))  -> 2-way LDS bank aliasing only (free).
// Pipeline: stage tile t+3 while computing tile t; s_waitcnt vmcnt(12) retires
// exactly tile t's 4 per-thread loads (never a full drain until the tail).
__global__ __launch_bounds__(512, 2) void gemm_kernel(
    const ushort* __restrict__ xbf,        // [8193][1024] bf16 (row 8192 = zeros)
    const ushort* __restrict__ wt,         // [8][4096][1024] bf16 (n-major)
    const float*  __restrict__ bias,       // [8][4096]
    const int*    __restrict__ slot_token, // [8][1280], empty -> ZROW
    float* __restrict__ out)               // [8][1280][4096]
{
    const int e  = blockIdx.z;
    const int mt = blockIdx.y;   // 0..4   (256 rows each)
    const int nt = blockIdx.x;   // 0..15  (256 cols each)
    __shared__ __align__(16) short lds[4][16384];   // 128 KiB
    const int tid  = threadIdx.x;
    const int lane = tid & 63;
    const int wave = tid >> 6;
    const int wr = wave >> 2;    // 0..1  -> 128 output rows
    const int wc = wave & 3;     // 0..3  -> 64 output cols

    // staging addresses (4 x 16B per thread per K-tile)
    const int r0 = tid >> 2;                        // 0..127
    const int kg = (tid & 3) ^ ((tid >> 3) & 3);    // inverse swizzle chunk
    const int tokA0 = slot_token[e * CAP + mt * 256 + r0];
    const int tokA1 = slot_token[e * CAP + mt * 256 + 128 + r0];
    const ushort* aptr0 = xbf + (size_t)tokA0 * DM + kg * 8;
    const ushort* aptr1 = xbf + (size_t)tokA1 * DM + kg * 8;
    const ushort* bptr0 = wt + ((size_t)e * DFF + (size_t)nt * 256 + r0) * DM + kg * 8;
    const ushort* bptr1 = bptr0 + (size_t)128 * DM;

    #define STAGE(T) do { \
        short* base_ = &lds[(T) & 3][0]; \
        size_t ko_ = (size_t)(T) * GBK; \
        gload16(aptr0 + ko_, base_ + tid * 8); \
        gload16(aptr1 + ko_, base_ + 4096 + tid * 8); \
        gload16(bptr0 + ko_, base_ + 8192 + tid * 8); \
        gload16(bptr1 + ko_, base_ + 12288 + tid * 8); \
    } while (0)

    // fragment LDS offsets (in shorts)
    const int fr = lane & 15, fc = lane >> 4;
    int aoff[8], boff[4];
    #pragma unroll
    for (int mi = 0; mi < 8; ++mi) {
        int r = wr * 128 + mi * 16 + fr;
        aoff[mi] = (r * 4 + (fc ^ ((r >> 1) & 3))) * 8;
    }
    #pragma unroll
    for (int ni = 0; ni < 4; ++ni) {
        int rn = wc * 64 + ni * 16 + fr;
        boff[ni] = 8192 + (rn * 4 + (fc ^ ((rn >> 1) & 3))) * 8;
    }

    f32x4 acc[8][4];
    #pragma unroll
    for (int mi = 0; mi < 8; ++mi)
        #pragma unroll
        for (int ni = 0; ni < 4; ++ni)
            acc[mi][ni] = (f32x4){0.f, 0.f, 0.f, 0.f};

    STAGE(0); STAGE(1); STAGE(2);
    for (int t = 0; t < 32; ++t) {
        if (t < 29) {
            STAGE(t + 3);
            asm volatile("s_waitcnt vmcnt(12)" ::: "memory");
        } else if (t == 29) {
            asm volatile("s_waitcnt vmcnt(8)" ::: "memory");
        } else if (t == 30) {
            asm volatile("s_waitcnt vmcnt(4)" ::: "memory");
        } else {
            asm volatile("s_waitcnt vmcnt(0)" ::: "memory");
        }
        __builtin_amdgcn_s_barrier();           // all waves' tile-t loads landed
        __builtin_amdgcn_sched_barrier(0);

        const short* L = &lds[t & 3][0];
        short8 af[8], bfr[4];
        #pragma unroll
        for (int mi = 0; mi < 8; ++mi) af[mi] = *(const short8*)(L + aoff[mi]);
        #pragma unroll
        for (int ni = 0; ni < 4; ++ni) bfr[ni] = *(const short8*)(L + boff[ni]);

        __builtin_amdgcn_s_setprio(1);
        #pragma unroll
        for (int mi = 0; mi < 8; ++mi)
            #pragma unroll
            for (int ni = 0; ni < 4; ++ni)
                acc[mi][ni] = __builtin_amdgcn_mfma_f32_16x16x32_bf16(af[mi], bfr[ni], acc[mi][ni], 0, 0, 0);
        __builtin_amdgcn_s_setprio(0);
        __builtin_amdgcn_sched_barrier(0);
        asm volatile("" ::: "memory");
        __builtin_amdgcn_s_barrier();           // buf[t&3] free for re-stage next iter
        asm volatile("" ::: "memory");
    }
    #undef STAGE

    float* orow = out + ((size_t)(e * CAP + mt * 256)) * DFF + (size_t)nt * 256;
    #pragma unroll
    for (int ni = 0; ni < 4; ++ni) {
        int c = wc * 64 + ni * 16 + fr;
        float bv = bias[e * DFF + nt * 256 + c];
        #pragma unroll
        for (int mi = 0; mi < 8; ++mi) {
            #pragma unroll
            for (int j = 0; j < 4; ++j) {
                int r = wr * 128 + mi * 16 + fc * 4 + j;
                orow[(size_t)r * DFF + c] = acc[mi][ni][j] + bv;
            }
        }
    }
}

// ---------------- scatter combine_weights + l_aux ----------------
__global__ __launch_bounds__(256) void scatter_kernel(const int* __restrict__ slot_token,
        const float* __restrict__ probs8, const float* __restrict__ laux,
        float* __restrict__ cmb, float* __restrict__ laux_out) {
    int s = blockIdx.x * 256 + threadIdx.x;   // 0..10239
    if (s < ECAP) {
        int tok = slot_token[s];
        if (tok < TOKENS) {
            int e = s / CAP;
            cmb[(size_t)tok * ECAP + s] = probs8[tok * 8 + e];
        }
    }
    if (blockIdx.x == 0 && threadIdx.x == 0) laux_out[0] = laux[0];
}

extern "C" void kernel_launch(void* const* d_in, const int* in_sizes, int n_in,
                              void* d_out, int out_size, void* d_ws, size_t ws_size,
                              hipStream_t stream) {
    const float* x  = (const float*)d_in[0];
    const float* gw = (const float*)d_in[1];
    const float* ew = (const float*)d_in[2];
    const float* eb = (const float*)d_in[3];

    float* out = (float*)d_out;                 // [8][1280][4096]
    float* cmb = out + OUT_ELEMS;               // [8192][8][1280]
    float* laux_out = cmb + CMB_ELEMS;          // scalar

    // small scratch in d_ws
    float* probs8 = (float*)d_ws;               // 8192*8
    int* top1 = (int*)(probs8 + TOKENS * 8);    // 8192
    int* slot_token = top1 + TOKENS;            // 10240
    float* laux_ws = (float*)(slot_token + ECAP);

    // big bf16 scratch inside the combine region (zeroed afterwards)
    ushort* wtbf = (ushort*)cmb;                       // 8*4096*1024 bf16 = 64 MB
    ushort* xbf  = wtbf + (size_t)NE * DFF * DM;       // 8193*1024 bf16 ≈ 16.8 MB

    gate_kernel<<<TOKENS / 4, 256, 0, stream>>>(x, gw, probs8, top1, xbf);
    rank_kernel<<<1, 512, 0, stream>>>(top1, probs8, slot_token, laux_ws);
    cvt_w<<<dim3(DFF / 32, DM / 32, NE), 256, 0, stream>>>(ew, wtbf);
    gemm_kernel<<<dim3(DFF / 256, CAP / 256, NE), 512, 0, stream>>>(xbf, wtbf, eb, slot_token, out);
    hipMemsetAsync(cmb, 0, CMB_ELEMS * sizeof(float), stream);
    scatter_kernel<<<(ECAP + 255) / 256, 256, 0, stream>>>(slot_token, probs8, laux_ws, cmb, laux_out);
}